// Round 2
// baseline (118.089 us; speedup 1.0000x reference)
//
#include <hip/hip_runtime.h>
#include <hip/hip_bf16.h>

typedef __bf16 bf8 __attribute__((ext_vector_type(8)));
typedef float f32x4 __attribute__((ext_vector_type(4)));

#define NBINS 129
#define WOUT 64
#define ROWB 516           // bytes per input row (129 f32)
#define OUTROWB 256        // bytes per output row (64 f32)
#define MT_STRIDE 168      // padded K stride (elems) for LDS M^T; 336B rows, 16B aligned
#define MT_ELEMS (WOUT * MT_STRIDE)

__global__ __launch_bounds__(256, 3)
void irfft_mm(const float* __restrict__ re,
              const float* __restrict__ im,
              const float* __restrict__ mr,
              const float* __restrict__ mi,
              float* __restrict__ out)
{
    __shared__ unsigned short mt[2 * MT_ELEMS];   // [mat][o][k] bf16, k padded 129->168 w/ zeros

    const int tid = threadIdx.x;

    // ---- stage M^T into LDS as bf16 (zero-fill pad, then transpose-fill) ----
    {
        int* p = (int*)mt;
        for (int i = tid; i < MT_ELEMS; i += 256) p[i] = 0;   // MT_ELEMS ints = whole array
    }
    __syncthreads();
    for (int e = tid; e < NBINS * WOUT; e += 256) {
        int k = e >> 6;        // bin n
        int c = e & 63;        // output col o
        __bf16 vr = (__bf16)mr[e];
        __bf16 vi = (__bf16)mi[e];
        mt[c * MT_STRIDE + k]            = __builtin_bit_cast(unsigned short, vr);
        mt[MT_ELEMS + c * MT_STRIDE + k] = __builtin_bit_cast(unsigned short, vi);
    }
    __syncthreads();

    const int lane = tid & 63;
    const int wave = tid >> 6;
    const int r16  = lane & 15;   // B col (data row within 16-block) / A row (o within 16-block)
    const int q    = lane >> 4;   // k sub-chunk (8 elems each)

    const long rowbase = (long)blockIdx.x * 256 + wave * 64;

    const char* reB = (const char*)re;
    const char* imB = (const char*)im;

    long rowoff[4];
    #pragma unroll
    for (int rb = 0; rb < 4; ++rb)
        rowoff[rb] = (rowbase + rb * 16 + r16) * (long)ROWB;

    int aoff[4];
    #pragma unroll
    for (int f = 0; f < 4; ++f)
        aoff[f] = (f * 16 + r16) * MT_STRIDE + q * 8;

    f32x4 acc[4][4];
    #pragma unroll
    for (int rb = 0; rb < 4; ++rb)
        #pragma unroll
        for (int f = 0; f < 4; ++f)
            acc[rb][f] = {0.0f, 0.0f, 0.0f, 0.0f};

    #pragma unroll
    for (int mat = 0; mat < 2; ++mat) {
        const char* src = mat ? imB : reB;
        const unsigned short* mtm = mt + mat * MT_ELEMS;

        #pragma unroll
        for (int t = 0; t < 5; ++t) {
            // ---- B frags: per-lane 32B f32 loads, convert to bf16 ----
            bf8 bfrag[4];
            if (t < 4) {
                #pragma unroll
                for (int rb = 0; rb < 4; ++rb) {
                    float f0[8];
                    __builtin_memcpy(f0, src + rowoff[rb] + (t * 32 + q * 8) * 4, 32);
                    bf8 v;
                    #pragma unroll
                    for (int j = 0; j < 8; ++j) v[j] = (__bf16)f0[j];
                    bfrag[rb] = v;
                }
            } else {
                // tail: only k=128 is real; pad lanes multiplied by LDS zeros anyway
                #pragma unroll
                for (int rb = 0; rb < 4; ++rb) {
                    bf8 z;
                    #pragma unroll
                    for (int j = 0; j < 8; ++j) z[j] = (__bf16)0.0f;
                    if (q == 0) {
                        float v = *(const float*)(src + rowoff[rb] + 128 * 4);
                        z[0] = (__bf16)v;
                    }
                    bfrag[rb] = z;
                }
            }

            // ---- A frags: M^T bf16 from LDS, 16B aligned ----
            bf8 afrag[4];
            #pragma unroll
            for (int f = 0; f < 4; ++f)
                afrag[f] = *(const bf8*)(mtm + aoff[f] + t * 32);

            // ---- MFMA ----
            #pragma unroll
            for (int rb = 0; rb < 4; ++rb)
                #pragma unroll
                for (int f = 0; f < 4; ++f)
                    acc[rb][f] = __builtin_amdgcn_mfma_f32_16x16x32_bf16(
                        afrag[f], bfrag[rb], acc[rb][f], 0, 0, 0);
        }
    }

    // ---- epilogue: D[o][r]; lane holds 4 contiguous cols (o = 16f + 4q + reg) of row r ----
    char* outB = (char*)out;
    #pragma unroll
    for (int rb = 0; rb < 4; ++rb) {
        long rptr = (rowbase + rb * 16 + r16) * (long)OUTROWB;
        #pragma unroll
        for (int f = 0; f < 4; ++f)
            *(f32x4*)(outB + rptr + f * 64 + q * 16) = acc[rb][f];
    }
}

extern "C" void kernel_launch(void* const* d_in, const int* in_sizes, int n_in,
                              void* d_out, int out_size, void* d_ws, size_t ws_size,
                              hipStream_t stream)
{
    const float* re = (const float*)d_in[0];
    const float* im = (const float*)d_in[1];
    const float* mr = (const float*)d_in[2];
    const float* mi = (const float*)d_in[3];
    float* out = (float*)d_out;

    long rows = (long)in_sizes[0] / NBINS;   // 256000
    int grid = (int)(rows / 256);            // 1000 (exact: 256000 % 256 == 0)
    irfft_mm<<<grid, 256, 0, stream>>>(re, im, mr, mi, out);
}

// Round 3
// 75.444 us; speedup vs baseline: 1.5652x; 1.5652x over previous
//
#include <hip/hip_runtime.h>
#include <hip/hip_bf16.h>

typedef __bf16 bf8 __attribute__((ext_vector_type(8)));
typedef float f32x4 __attribute__((ext_vector_type(4)));
typedef unsigned short u16x4 __attribute__((ext_vector_type(4)));

#define NBINS 129
#define SROWS 64                 // rows per sub-tile
#define KSTR 136                 // LDS k-stride (elems); 272 B rows -> conflict-free-ish b128
#define MATOFF (SROWS * KSTR)    // 8704 elems per matrix
#define SUBTILES 4

__device__ __forceinline__ unsigned short f2bf(float x) {
    return __builtin_bit_cast(unsigned short, (__bf16)x);
}

__global__ __launch_bounds__(256, 4)
void irfft_mm(const float* __restrict__ re,
              const float* __restrict__ im,
              const float* __restrict__ mr,
              const float* __restrict__ mi,
              float* __restrict__ out)
{
    __shared__ unsigned short lds[2 * MATOFF];   // 34816 B -> 4 blocks/CU

    const int tid  = threadIdx.x;
    const int lane = tid & 63;
    const int w    = tid >> 6;   // wave id = output-col block (16 cols per wave)
    const int r16  = lane & 15;
    const int q    = lane >> 4;

    // ---- A fragments (M^T) straight from global into registers; L2-hot, tiny ----
    // afr[m][t] lane (r16,q) holds M^T[o = w*16+r16][k = t*32+q*8 .. +8]
    bf8 afr[2][4];
    #pragma unroll
    for (int m = 0; m < 2; ++m) {
        const float* M = m ? mi : mr;
        #pragma unroll
        for (int t = 0; t < 4; ++t) {
            bf8 v;
            #pragma unroll
            for (int j = 0; j < 8; ++j)
                v[j] = (__bf16)M[(t * 32 + q * 8 + j) * 64 + w * 16 + r16];
            afr[m][t] = v;
        }
    }
    // k=128 tail coefficients, full f32: M[128][o], o = w*16 + q*4 + jj
    const f32x4 mt0 = *(const f32x4*)(mr + 128 * 64 + w * 16 + q * 4);
    const f32x4 mt1 = *(const f32x4*)(mi + 128 * 64 + w * 16 + q * 4);

    for (int st = 0; st < SUBTILES; ++st) {
        const int rowbase = (blockIdx.x * SUBTILES + st) * SROWS;

        // ---- stage 64 rows x {re,im}, k in [0,128), coalesced float4 loads ----
        // chunk F in [0,4096): mat = F>>11 (compile-time per j), row = (F>>5)&63, c = F&31
        #pragma unroll
        for (int j = 0; j < 16; ++j) {
            const int F   = tid + j * 256;
            const int row = (F >> 5) & 63;
            const int c   = F & 31;
            const float* srcp = (j < 8) ? re : im;
            f32x4 v;
            __builtin_memcpy(&v, srcp + (rowbase + row) * NBINS + c * 4, 16);
            u16x4 h;
            h[0] = f2bf(v[0]); h[1] = f2bf(v[1]);
            h[2] = f2bf(v[2]); h[3] = f2bf(v[3]);
            *(u16x4*)&lds[(j >> 3) * MATOFF + row * KSTR + c * 4] = h;  // 8B aligned
        }
        // k=128 tail elements (one per row per mat)
        if (tid < 128) {
            const float* srcp = (tid < 64) ? re : im;
            const int row = tid & 63;
            const float v = srcp[(rowbase + row) * NBINS + 128];
            lds[(tid >> 6) * MATOFF + row * KSTR + 128] = f2bf(v);
        }
        __syncthreads();

        f32x4 acc[4];
        #pragma unroll
        for (int rb = 0; rb < 4; ++rb) acc[rb] = {0.0f, 0.0f, 0.0f, 0.0f};

        #pragma unroll
        for (int m = 0; m < 2; ++m) {
            #pragma unroll
            for (int t = 0; t < 4; ++t) {
                bf8 bfr[4];
                #pragma unroll
                for (int rb = 0; rb < 4; ++rb)
                    bfr[rb] = *(const bf8*)&lds[m * MATOFF + (rb * 16 + r16) * KSTR
                                                + t * 32 + q * 8];   // 16B aligned
                #pragma unroll
                for (int rb = 0; rb < 4; ++rb)
                    acc[rb] = __builtin_amdgcn_mfma_f32_16x16x32_bf16(
                        afr[m][t], bfr[rb], acc[rb], 0, 0, 0);
            }
            // ---- k = 128 rank-1 update in f32 VALU (avoids a 5th padded K-step) ----
            const f32x4 mt = (m == 0) ? mt0 : mt1;
            #pragma unroll
            for (int rb = 0; rb < 4; ++rb) {
                const unsigned short h = lds[m * MATOFF + (rb * 16 + r16) * KSTR + 128];
                const float xt = (float)__builtin_bit_cast(__bf16, h);
                #pragma unroll
                for (int jj = 0; jj < 4; ++jj)
                    acc[rb][jj] += xt * mt[jj];
            }
        }
        __syncthreads();   // protects LDS for next sub-tile's staging

        // ---- epilogue: D[o][r]; lane holds o = w*16 + q*4 + jj for data row rb*16+r16 ----
        // per row: 4 q-chunks cover 64 contiguous, 64B-aligned bytes -> full-line stores
        #pragma unroll
        for (int rb = 0; rb < 4; ++rb)
            *(f32x4*)(out + (rowbase + rb * 16 + r16) * 64 + w * 16 + q * 4) = acc[rb];
    }
}

extern "C" void kernel_launch(void* const* d_in, const int* in_sizes, int n_in,
                              void* d_out, int out_size, void* d_ws, size_t ws_size,
                              hipStream_t stream)
{
    const float* re = (const float*)d_in[0];
    const float* im = (const float*)d_in[1];
    const float* mr = (const float*)d_in[2];
    const float* mi = (const float*)d_in[3];
    float* out = (float*)d_out;

    const long rows = (long)in_sizes[0] / NBINS;          // 256000
    const int grid = (int)(rows / (SUBTILES * SROWS));    // 1000 (exact)
    irfft_mm<<<grid, 256, 0, stream>>>(re, im, mr, mi, out);
}

// Round 4
// 67.873 us; speedup vs baseline: 1.7399x; 1.1116x over previous
//
#include <hip/hip_runtime.h>
#include <hip/hip_bf16.h>

typedef __bf16 bf8 __attribute__((ext_vector_type(8)));
typedef float f32x4 __attribute__((ext_vector_type(4)));
typedef unsigned short u16x4 __attribute__((ext_vector_type(4)));

#define NBINS 129
#define ROWS_IT 32               // rows per iteration
#define ITERS 8                  // iterations per block (256 rows/block)
#define KSTR 136                 // LDS k-stride (elems); 272B rows, 16B-aligned chunks
#define MATOFF (ROWS_IT * KSTR)  // 4352 elems per matrix per buffer
#define BUFE (2 * MATOFF)        // 8704 elems per buffer (17408 B)

__device__ __forceinline__ unsigned short f2bf(float x) {
    return __builtin_bit_cast(unsigned short, (__bf16)x);
}

__device__ __forceinline__ void issue_loads(const float* __restrict__ re,
                                            const float* __restrict__ im,
                                            int rowbase, int tid,
                                            f32x4* v, float* tl)
{
    #pragma unroll
    for (int j = 0; j < 8; ++j) {
        const int F = tid + j * 256;
        const float* srcp = (j < 4) ? re : im;
        const int row = (F >> 5) & 31;
        const int c   = F & 31;
        __builtin_memcpy(&v[j], srcp + (long)(rowbase + row) * NBINS + c * 4, 16);
    }
    float t = 0.0f;
    if (tid < 64) {
        const float* srcp = (tid < 32) ? re : im;
        t = srcp[(long)(rowbase + (tid & 31)) * NBINS + 128];
    }
    *tl = t;
}

__global__ __launch_bounds__(256, 4)
void irfft_mm(const float* __restrict__ re,
              const float* __restrict__ im,
              const float* __restrict__ mr,
              const float* __restrict__ mi,
              float* __restrict__ out)
{
    __shared__ unsigned short lds[2][BUFE];   // 34816 B total -> 4 blocks/CU

    const int tid  = threadIdx.x;
    const int lane = tid & 63;
    const int w    = tid >> 6;   // wave id = 16-col block of output
    const int r16  = lane & 15;
    const int q    = lane >> 4;

    const int blockrow = blockIdx.x * (ROWS_IT * ITERS);

    // ---- prefetch iteration 0 (before the long A-fragment prologue) ----
    f32x4 v[8]; float tl;
    issue_loads(re, im, blockrow, tid, v, &tl);

    // ---- A fragments (M^T) from global into registers; L2/L3-hot ----
    bf8 afr[2][4];
    #pragma unroll
    for (int m = 0; m < 2; ++m) {
        const float* M = m ? mi : mr;
        #pragma unroll
        for (int t = 0; t < 4; ++t) {
            bf8 a;
            #pragma unroll
            for (int j = 0; j < 8; ++j)
                a[j] = (__bf16)M[(t * 32 + q * 8 + j) * 64 + w * 16 + r16];
            afr[m][t] = a;
        }
    }
    const f32x4 mt0 = *(const f32x4*)(mr + 128 * 64 + w * 16 + q * 4);
    const f32x4 mt1 = *(const f32x4*)(mi + 128 * 64 + w * 16 + q * 4);

    for (int it = 0; it < ITERS; ++it) {
        unsigned short* buf = lds[it & 1];
        const int rowbase = blockrow + it * ROWS_IT;

        // ---- convert + stage the loads that arrived during previous compute ----
        #pragma unroll
        for (int j = 0; j < 8; ++j) {
            const int F   = tid + j * 256;
            const int mat = j >> 2;
            const int row = (F >> 5) & 31;
            const int c   = F & 31;
            u16x4 h;
            h[0] = f2bf(v[j][0]); h[1] = f2bf(v[j][1]);
            h[2] = f2bf(v[j][2]); h[3] = f2bf(v[j][3]);
            *(u16x4*)&buf[mat * MATOFF + row * KSTR + c * 4] = h;
        }
        if (tid < 64)
            buf[(tid >> 5) * MATOFF + (tid & 31) * KSTR + 128] = f2bf(tl);

        // ---- prefetch next iteration (stays in flight across the raw barrier) ----
        if (it + 1 < ITERS)
            issue_loads(re, im, rowbase + ROWS_IT, tid, v, &tl);

        // LDS writes visible to workgroup; do NOT drain vmcnt (prefetch in flight)
        asm volatile("s_waitcnt lgkmcnt(0)" ::: "memory");
        __builtin_amdgcn_s_barrier();
        asm volatile("" ::: "memory");

        // ---- compute 32 rows x 16 cols per wave ----
        f32x4 acc[2];
        acc[0] = {0.0f, 0.0f, 0.0f, 0.0f};
        acc[1] = {0.0f, 0.0f, 0.0f, 0.0f};

        #pragma unroll
        for (int m = 0; m < 2; ++m) {
            #pragma unroll
            for (int t = 0; t < 4; ++t) {
                bf8 b0 = *(const bf8*)&buf[m * MATOFF + r16 * KSTR + t * 32 + q * 8];
                bf8 b1 = *(const bf8*)&buf[m * MATOFF + (16 + r16) * KSTR + t * 32 + q * 8];
                acc[0] = __builtin_amdgcn_mfma_f32_16x16x32_bf16(afr[m][t], b0, acc[0], 0, 0, 0);
                acc[1] = __builtin_amdgcn_mfma_f32_16x16x32_bf16(afr[m][t], b1, acc[1], 0, 0, 0);
            }
            // k = 128 rank-1 tail in f32 VALU
            const f32x4 mt = m ? mt1 : mt0;
            #pragma unroll
            for (int rb = 0; rb < 2; ++rb) {
                const unsigned short h = buf[m * MATOFF + (rb * 16 + r16) * KSTR + 128];
                const float xt = (float)__builtin_bit_cast(__bf16, h);
                #pragma unroll
                for (int jj = 0; jj < 4; ++jj)
                    acc[rb][jj] += xt * mt[jj];
            }
        }

        // ---- coalesced f32x4 stores (64B-aligned full lines per 4 q-chunks) ----
        #pragma unroll
        for (int rb = 0; rb < 2; ++rb)
            *(f32x4*)(out + (long)(rowbase + rb * 16 + r16) * 64 + w * 16 + q * 4) = acc[rb];
    }
}

extern "C" void kernel_launch(void* const* d_in, const int* in_sizes, int n_in,
                              void* d_out, int out_size, void* d_ws, size_t ws_size,
                              hipStream_t stream)
{
    const float* re = (const float*)d_in[0];
    const float* im = (const float*)d_in[1];
    const float* mr = (const float*)d_in[2];
    const float* mi = (const float*)d_in[3];
    float* out = (float*)d_out;

    const long rows = (long)in_sizes[0] / NBINS;          // 256000
    const int grid = (int)(rows / (ROWS_IT * ITERS));     // 1000 (exact)
    irfft_mm<<<grid, 256, 0, stream>>>(re, im, mr, mi, out);
}